// Round 7
// baseline (184.194 us; speedup 1.0000x reference)
//
#include <hip/hip_runtime.h>
#include <math.h>

#define KE 14.3996f
#define R_MAX 6.0f

// P8: short4 per atom {qx,qy,qz (step 1/512), Z}; exact path (validated R5, absmax 0.0)
#define PSCALE 512.0f
#define INV_PS2 (1.0f / (512.0f * 512.0f))
// C4: packed 10:10:10 coarse coords, step 0.1, bias 512 (range ~±51.1)
// keep iff int d2 <= 3820 (<=> coarse_dr <= 6.181); max screen err sqrt(3)*0.1=0.173
// => conservative: any true dr < 6.0 survives. Cutoff has zero slope at R_MAX, so
// boundary-region edges contribute ~0 either way.
#define D2_KEEP 3820

// ws layout (floats):
//  [0] ae [1] 1/an [2] pre   [3..6] coeffs   [7..10] exps
//  [16..79] powtab[z]=z^ae
//  [128 ..)             C4 table (uint32/atom)
//  [128+131072 ..)      P8 table (short4/atom)
#define WS_POW 16
#define WS_C4  128
#define WS_P8  (128 + 131072)

typedef short s4 __attribute__((ext_vector_type(4)));

__device__ __forceinline__ float softplus_f(float x) {
    return log1pf(expf(x));
}

__global__ void zbl_prep(const float* __restrict__ a_exp,
                         const float* __restrict__ a_num,
                         const float* __restrict__ coefficients,
                         const float* __restrict__ exponents,
                         const float* __restrict__ rep_scale,
                         float* __restrict__ ws,
                         float* __restrict__ out) {
    int t = threadIdx.x;  // 1 block x 64 threads
    float ae = softplus_f(a_exp[0]);
    if (t == 0) {
        ws[0] = ae;
        ws[1] = 1.0f / softplus_f(a_num[0]);
        ws[2] = 0.5f * KE * softplus_f(rep_scale[0]);
        out[0] = 0.0f;   // d_out poisoned 0xAA before every timed call
    }
    if (t < 4) {
        ws[3 + t] = softplus_f(coefficients[t]);
        ws[7 + t] = softplus_f(exponents[t]);
    }
    ws[WS_POW + t] = (t > 0) ? expf(ae * logf((float)t)) : 0.0f;
}

__global__ __launch_bounds__(256) void atom_prep(const float* __restrict__ R,
                                                 const int* __restrict__ Z,
                                                 unsigned int* __restrict__ C4,
                                                 s4* __restrict__ P8,
                                                 int n) {
    int i = blockIdx.x * blockDim.x + threadIdx.x;
    if (i < n) {
        const float x = R[3 * i + 0], y = R[3 * i + 1], z = R[3 * i + 2];
        s4 v;
        v.x = (short)lrintf(x * PSCALE);
        v.y = (short)lrintf(y * PSCALE);
        v.z = (short)lrintf(z * PSCALE);
        v.w = (short)Z[i];
        P8[i] = v;
        int cx = (int)lrintf(x * 10.0f) + 512;
        int cy = (int)lrintf(y * 10.0f) + 512;
        int cz = (int)lrintf(z * 10.0f) + 512;
        cx = min(max(cx, 0), 1023);
        cy = min(max(cy, 0), 1023);
        cz = min(max(cz, 0), 1023);
        C4[i] = (unsigned int)(cx | (cy << 10) | (cz << 20));
    }
}

__device__ __forceinline__ int coarse_keep(unsigned int ca, unsigned int cb) {
    const int dx = (int)(ca & 1023u) - (int)(cb & 1023u);
    const int dy = (int)((ca >> 10) & 1023u) - (int)((cb >> 10) & 1023u);
    const int dz = (int)((ca >> 20) & 1023u) - (int)((cb >> 20) & 1023u);
    const int d2 = dx * dx + dy * dy + dz * dz;   // exact integer screen
    return d2 <= D2_KEEP;
}

// exact path — only executed by surviving lanes (~2.3%)
__device__ __forceinline__ float edge_term(const s4* __restrict__ P8, int i, int j,
                                           const float* __restrict__ R,
                                           const float* __restrict__ spow,
                                           float inv_an,
                                           float c0, float c1, float c2, float c3,
                                           float e0, float e1, float e2, float e3) {
    if (i == j) return 0.0f;
    const s4 pa = P8[i];
    const s4 pb = P8[j];
    const float dx = (float)(pb.x - pa.x);
    const float dy = (float)(pb.y - pa.y);
    const float dz = (float)(pb.z - pa.z);
    const float dr2 = (dx * dx + dy * dy + dz * dz) * INV_PS2;
    if (dr2 >= R_MAX * R_MAX) return 0.0f;   // screen is conservative: re-check exact
    float dr;
    if (dr2 < 0.1225f) {
        // rare: 1/dr^2 sensitivity — recompute from exact fp32 R
        const float ax = R[3 * i], ay = R[3 * i + 1], az = R[3 * i + 2];
        const float bx = R[3 * j], by = R[3 * j + 1], bz = R[3 * j + 2];
        const float fx = bx - ax, fy = by - ay, fz = bz - az;
        dr = fmaxf(__fsqrt_rn(fx * fx + fy * fy + fz * fz), 0.02f);
    } else {
        dr = __fsqrt_rn(dr2);
    }
    const float zi = (float)pa.w;
    const float zj = (float)pb.w;
    const float ppa = spow[(int)pa.w] + spow[(int)pb.w];   // Z_i^ae + Z_j^ae
    const float dist = dr * ppa * inv_an;
    const float f = c0 * __expf(-e0 * dist) + c1 * __expf(-e1 * dist)
                  + c2 * __expf(-e2 * dist) + c3 * __expf(-e3 * dist);
    const float cut = 0.5f * (__cosf((float)M_PI / R_MAX * dr) + 1.0f);
    return zi * zj / dr * f * cut;
}

__global__ __launch_bounds__(256) void zbl_edges(
        const unsigned int* __restrict__ C4,
        const s4*    __restrict__ P8,
        const float* __restrict__ R,
        const int*   __restrict__ idx_i,
        const int*   __restrict__ idx_j,
        const float* __restrict__ ws,
        float*       __restrict__ out,
        int nE) {
    __shared__ float spow[64];
    __shared__ float ssc[11];
    if (threadIdx.x < 64) spow[threadIdx.x] = ws[WS_POW + threadIdx.x];
    if (threadIdx.x < 11) ssc[threadIdx.x] = ws[threadIdx.x];
    __syncthreads();

    const float inv_an = ssc[1];
    const float c0 = ssc[3], c1 = ssc[4], c2 = ssc[5], c3 = ssc[6];
    const float e0 = ssc[7], e1 = ssc[8], e2 = ssc[9], e3 = ssc[10];

    float local = 0.0f;
    const int tid = blockIdx.x * blockDim.x + threadIdx.x;
    const int nB = nE >> 2;          // 4 edges per lane

    if (tid < nB) {
        const int e = tid << 2;
        // coalesced idx loads
        const int4 ii = *(const int4*)(idx_i + e);
        const int4 jj = *(const int4*)(idx_j + e);
        // 8 independent 4B coarse gathers, all in flight before any use (MLP)
        const unsigned int ca0 = C4[ii.x], cb0 = C4[jj.x];
        const unsigned int ca1 = C4[ii.y], cb1 = C4[jj.y];
        const unsigned int ca2 = C4[ii.z], cb2 = C4[jj.z];
        const unsigned int ca3 = C4[ii.w], cb3 = C4[jj.w];
        // exact integer screen; refine is per-lane predicated — masked-out
        // lanes issue NO memory requests (this is the delta vs R6's
        // always-execute broadcast refine, which cost ~10-15us)
        if (coarse_keep(ca0, cb0))
            local += edge_term(P8, ii.x, jj.x, R, spow, inv_an, c0,c1,c2,c3, e0,e1,e2,e3);
        if (coarse_keep(ca1, cb1))
            local += edge_term(P8, ii.y, jj.y, R, spow, inv_an, c0,c1,c2,c3, e0,e1,e2,e3);
        if (coarse_keep(ca2, cb2))
            local += edge_term(P8, ii.z, jj.z, R, spow, inv_an, c0,c1,c2,c3, e0,e1,e2,e3);
        if (coarse_keep(ca3, cb3))
            local += edge_term(P8, ii.w, jj.w, R, spow, inv_an, c0,c1,c2,c3, e0,e1,e2,e3);
    }
    // tail (nE % 4 != 0): last block, exact path only
    if (blockIdx.x == gridDim.x - 1) {
        for (int k = (nB << 2) + threadIdx.x; k < nE; k += blockDim.x) {
            local += edge_term(P8, idx_i[k], idx_j[k], R, spow, inv_an,
                               c0,c1,c2,c3, e0,e1,e2,e3);
        }
    }

    for (int off = 32; off > 0; off >>= 1)
        local += __shfl_down(local, off);

    __shared__ float wsum[4];
    const int lane = threadIdx.x & 63;
    const int wave = threadIdx.x >> 6;
    if (lane == 0) wsum[wave] = local;
    __syncthreads();
    if (threadIdx.x == 0) {
        const float s = (wsum[0] + wsum[1] + wsum[2] + wsum[3]) * ssc[2];
        atomicAdd(out, s);
    }
}

extern "C" void kernel_launch(void* const* d_in, const int* in_sizes, int n_in,
                              void* d_out, int out_size, void* d_ws, size_t ws_size,
                              hipStream_t stream) {
    const float* R     = (const float*)d_in[0];
    const int*   Z     = (const int*)d_in[1];
    const int*   idx   = (const int*)d_in[2];
    const float* a_exp = (const float*)d_in[3];
    const float* a_num = (const float*)d_in[4];
    const float* coef  = (const float*)d_in[5];
    const float* expo  = (const float*)d_in[6];
    const float* rs    = (const float*)d_in[7];

    float* out = (float*)d_out;
    float* ws  = (float*)d_ws;

    const int nA = in_sizes[0] / 3;
    const int nE = in_sizes[2] / 2;
    const int* idx_i = idx;
    const int* idx_j = idx + nE;

    unsigned int* C4 = (unsigned int*)(ws + WS_C4);
    s4* P8 = (s4*)(ws + WS_P8);

    zbl_prep<<<1, 64, 0, stream>>>(a_exp, a_num, coef, expo, rs, ws, out);
    atom_prep<<<(nA + 255) / 256, 256, 0, stream>>>(R, Z, C4, P8, nA);

    const int block = 256;
    const int nB = nE >> 2;
    const int grid = (nB + block - 1) / block;   // 6250 blocks for 6.4M edges
    zbl_edges<<<grid, block, 0, stream>>>(C4, P8, R, idx_i, idx_j, ws, out, nE);
}

// Round 8
// 124.373 us; speedup vs baseline: 1.4810x; 1.4810x over previous
//
#include <hip/hip_runtime.h>
#include <math.h>

#define KE 14.3996f
#define R_MAX 6.0f

// P8 exact path: short4 {qx,qy,qz (step 1/512), Z} — validated R5/R6, absmax 0.0
#define PSCALE 512.0f
#define INV_PS2 (1.0f / (512.0f * 512.0f))

// ws float-index layout: [0] ae [1] 1/an [2] pre  [3..6] coeffs  [7..10] exps
// [16..79] powtab[z]=z^ae.  Byte offset 512+: XY table, N4 table, P8 table.
#define WS_POW_F 16

typedef short s4 __attribute__((ext_vector_type(4)));

__device__ __forceinline__ float softplus_f(float x) { return log1pf(expf(x)); }

__global__ void zbl_prep(const float* __restrict__ a_exp,
                         const float* __restrict__ a_num,
                         const float* __restrict__ coefficients,
                         const float* __restrict__ exponents,
                         const float* __restrict__ rep_scale,
                         float* __restrict__ ws,
                         float* __restrict__ out) {
    int t = threadIdx.x;  // 1 block x 64 threads
    float ae = softplus_f(a_exp[0]);
    if (t == 0) {
        ws[0] = ae;
        ws[1] = 1.0f / softplus_f(a_num[0]);
        ws[2] = 0.5f * KE * softplus_f(rep_scale[0]);
        out[0] = 0.0f;   // d_out poisoned 0xAA before every timed call
    }
    if (t < 4) {
        ws[3 + t] = softplus_f(coefficients[t]);
        ws[7 + t] = softplus_f(exponents[t]);
    }
    ws[WS_POW_F + t] = (t > 0) ? expf(ae * logf((float)t)) : 0.0f;
}

// Screen codes.
// XY byte: 4-bit bins per axis, width 2, covering [-16,16], clamped.
//   discard iff |dbin| >= 4 on either axis  ==> |delta| >= 6  (proof: non-clamp
//   gap = 2*db-2 >= 6; clamp bins only extend outward). Conservative-exact
//   because cutoff(dr>=6) == 0.
// N4 nibble: 2-bit bins per axis, width 8, covering [-16,16], clamped.
//   discard iff |dbin| >= 2 ==> |delta| >= 8 > 6.
__global__ __launch_bounds__(256) void atom_prep(const float* __restrict__ R,
                                                 const int* __restrict__ Z,
                                                 unsigned char* __restrict__ XY,
                                                 unsigned char* __restrict__ N4,
                                                 s4* __restrict__ P8,
                                                 int nA) {
    int i = blockIdx.x * blockDim.x + threadIdx.x;
    if (i < nA) {
        const float x = R[3 * i + 0], y = R[3 * i + 1], z = R[3 * i + 2];
        s4 v;
        v.x = (short)lrintf(x * PSCALE);
        v.y = (short)lrintf(y * PSCALE);
        v.z = (short)lrintf(z * PSCALE);
        v.w = (short)Z[i];
        P8[i] = v;
        int bx = min(max((int)floorf((x + 16.0f) * 0.5f), 0), 15);
        int by = min(max((int)floorf((y + 16.0f) * 0.5f), 0), 15);
        XY[i] = (unsigned char)(bx | (by << 4));
    }
    const int half = (nA + 1) >> 1;
    if (i < half) {
        unsigned int byte = 0;
        for (int k = 0; k < 2; ++k) {
            const int a = 2 * i + k;
            if (a < nA) {
                const float x = R[3 * a + 0], y = R[3 * a + 1];
                int cx = min(max((int)floorf((x + 16.0f) * 0.125f), 0), 3);
                int cy = min(max((int)floorf((y + 16.0f) * 0.125f), 0), 3);
                byte |= (unsigned int)(cx | (cy << 2)) << (4 * k);
            }
        }
        N4[i] = (unsigned char)byte;
    }
}

// exact per-edge term (validated R5/R6: absmax 0.0)
__device__ __forceinline__ float edge_term(const s4* __restrict__ P8, int i, int j,
                                           const float* __restrict__ R,
                                           const float* __restrict__ spow,
                                           float inv_an,
                                           float c0, float c1, float c2, float c3,
                                           float e0, float e1, float e2, float e3) {
    if (i == j) return 0.0f;
    const s4 pa = P8[i];
    const s4 pb = P8[j];
    const float dx = (float)(pb.x - pa.x);
    const float dy = (float)(pb.y - pa.y);
    const float dz = (float)(pb.z - pa.z);
    const float dr2 = (dx * dx + dy * dy + dz * dz) * INV_PS2;
    if (dr2 >= R_MAX * R_MAX) return 0.0f;   // screens are conservative: exact re-check
    float dr;
    if (dr2 < 0.1225f) {
        // rare: 1/dr^2 sensitivity — recompute from exact fp32 R
        const float ax = R[3 * i], ay = R[3 * i + 1], az = R[3 * i + 2];
        const float bx = R[3 * j], by = R[3 * j + 1], bz = R[3 * j + 2];
        const float fx = bx - ax, fy = by - ay, fz = bz - az;
        dr = fmaxf(__fsqrt_rn(fx * fx + fy * fy + fz * fz), 0.02f);
    } else {
        dr = __fsqrt_rn(dr2);
    }
    const float zi = (float)pa.w;
    const float zj = (float)pb.w;
    const float ppa = spow[(int)pa.w] + spow[(int)pb.w];
    const float dist = dr * ppa * inv_an;
    const float f = c0 * __expf(-e0 * dist) + c1 * __expf(-e1 * dist)
                  + c2 * __expf(-e2 * dist) + c3 * __expf(-e3 * dist);
    const float cut = 0.5f * (__cosf((float)M_PI / R_MAX * dr) + 1.0f);
    return zi * zj / dr * f * cut;
}

#define PUSH_IF(keep, iv, jv)                                                  \
    {                                                                          \
        const bool _k = (keep);                                                \
        const unsigned long long _m = __ballot(_k);                            \
        const int _nk = __popcll(_m);                                          \
        int _wb = 0;                                                           \
        if (lane == 0 && _nk) _wb = atomicAdd(&cnt, _nk);                      \
        _wb = __shfl(_wb, 0);                                                  \
        if (_k) {                                                              \
            const int _pos = _wb + __popcll(_m & ((1ull << lane) - 1));        \
            pairs[_pos] = ((unsigned long long)(unsigned int)(iv) << 32)       \
                          | (unsigned int)(jv);                                \
        }                                                                      \
    }

// BIG: full byte XY table in dynamic LDS (~100 KB), 2 edges/thread/chunk.
__global__ __launch_bounds__(1024) void zbl_edges_big(
        const unsigned char* __restrict__ XY,
        const s4*    __restrict__ P8,
        const float* __restrict__ R,
        const int*   __restrict__ idx_i,
        const int*   __restrict__ idx_j,
        const float* __restrict__ ws,
        float*       __restrict__ out,
        int nE, int nA) {
    extern __shared__ unsigned char lds[];          // XY table (padded to 16)
    __shared__ unsigned long long pairs[2048];
    __shared__ float spow[64];
    __shared__ float ssc[11];
    __shared__ float wsum[16];
    __shared__ int cnt;

    const int tid = threadIdx.x;
    const int lane = tid & 63;
    const int nbytes = (nA + 15) & ~15;
    for (int off = tid * 16; off < nbytes; off += 1024 * 16)
        *(int4*)(lds + off) = *(const int4*)(XY + off);
    if (tid < 64) spow[tid] = ws[WS_POW_F + tid];
    if (tid < 11) ssc[tid] = ws[tid];
    __syncthreads();

    const float inv_an = ssc[1];
    const float c0 = ssc[3], c1 = ssc[4], c2 = ssc[5], c3 = ssc[6];
    const float e0 = ssc[7], e1 = ssc[8], e2 = ssc[9], e3 = ssc[10];

    float local = 0.0f;
    for (int base = blockIdx.x * 2048; base < nE; base += gridDim.x * 2048) {
        __syncthreads();                 // prior dense phase done
        if (tid == 0) cnt = 0;
        __syncthreads();
        const int e0i = base + tid * 2;
        const int eA = min(e0i, nE - 2);           // stays even; in-bounds
        const int2 ii = *(const int2*)(idx_i + eA);
        const int2 jj = *(const int2*)(idx_j + eA);
        const unsigned int c_i0 = lds[ii.x], c_j0 = lds[jj.x];
        const unsigned int c_i1 = lds[ii.y], c_j1 = lds[jj.y];
        const bool v0 = (e0i < nE), v1 = (e0i + 1 < nE);
        const bool k0 = v0 && (abs((int)(c_i0 & 15u) - (int)(c_j0 & 15u)) <= 3)
                           && (abs((int)(c_i0 >> 4) - (int)(c_j0 >> 4)) <= 3);
        const bool k1 = v1 && (abs((int)(c_i1 & 15u) - (int)(c_j1 & 15u)) <= 3)
                           && (abs((int)(c_i1 >> 4) - (int)(c_j1 >> 4)) <= 3);
        PUSH_IF(k0, ii.x, jj.x)
        PUSH_IF(k1, ii.y, jj.y)
        __syncthreads();
        const int n = cnt;
        for (int t = tid; t < n; t += 1024) {
            const unsigned long long p = pairs[t];
            const int i = (int)(p >> 32);
            const int j = (int)(p & 0xffffffffu);
            local += edge_term(P8, i, j, R, spow, inv_an, c0,c1,c2,c3, e0,e1,e2,e3);
        }
    }

    for (int off = 32; off > 0; off >>= 1)
        local += __shfl_down(local, off);
    const int wave = tid >> 6;
    if (lane == 0) wsum[wave] = local;
    __syncthreads();
    if (tid == 0) {
        float s = 0.0f;
        for (int w = 0; w < 16; ++w) s += wsum[w];
        atomicAdd(out, s * ssc[2]);
    }
}

// SAFE (<=64 KB LDS): 4-bit/atom nibble table (~50 KB), 1 edge/thread/chunk.
__global__ __launch_bounds__(1024) void zbl_edges_safe(
        const unsigned char* __restrict__ N4,
        const s4*    __restrict__ P8,
        const float* __restrict__ R,
        const int*   __restrict__ idx_i,
        const int*   __restrict__ idx_j,
        const float* __restrict__ ws,
        float*       __restrict__ out,
        int nE, int nA) {
    extern __shared__ unsigned char lds[];          // nibble table (padded to 16)
    __shared__ unsigned long long pairs[1024];
    __shared__ float spow[64];
    __shared__ float ssc[11];
    __shared__ float wsum[16];
    __shared__ int cnt;

    const int tid = threadIdx.x;
    const int lane = tid & 63;
    const int half = (nA + 1) >> 1;
    const int nbytes = (half + 15) & ~15;
    for (int off = tid * 16; off < nbytes; off += 1024 * 16)
        *(int4*)(lds + off) = *(const int4*)(N4 + off);
    if (tid < 64) spow[tid] = ws[WS_POW_F + tid];
    if (tid < 11) ssc[tid] = ws[tid];
    __syncthreads();

    const float inv_an = ssc[1];
    const float c0 = ssc[3], c1 = ssc[4], c2 = ssc[5], c3 = ssc[6];
    const float e0 = ssc[7], e1 = ssc[8], e2 = ssc[9], e3 = ssc[10];

    float local = 0.0f;
    for (int base = blockIdx.x * 1024; base < nE; base += gridDim.x * 1024) {
        __syncthreads();
        if (tid == 0) cnt = 0;
        __syncthreads();
        const int e = base + tid;
        const int eA = min(e, nE - 1);
        const int i = idx_i[eA];
        const int j = idx_j[eA];
        const unsigned int bi = lds[i >> 1], bj = lds[j >> 1];
        const unsigned int ni = (i & 1) ? (bi >> 4) : (bi & 15u);
        const unsigned int nj = (j & 1) ? (bj >> 4) : (bj & 15u);
        const bool keep = (e < nE)
                       && (abs((int)(ni & 3u) - (int)(nj & 3u)) <= 1)
                       && (abs((int)(ni >> 2) - (int)(nj >> 2)) <= 1);
        PUSH_IF(keep, i, j)
        __syncthreads();
        const int n = cnt;
        for (int t = tid; t < n; t += 1024) {
            const unsigned long long p = pairs[t];
            const int pi = (int)(p >> 32);
            const int pj = (int)(p & 0xffffffffu);
            local += edge_term(P8, pi, pj, R, spow, inv_an, c0,c1,c2,c3, e0,e1,e2,e3);
        }
    }

    for (int off = 32; off > 0; off >>= 1)
        local += __shfl_down(local, off);
    const int wave = tid >> 6;
    if (lane == 0) wsum[wave] = local;
    __syncthreads();
    if (tid == 0) {
        float s = 0.0f;
        for (int w = 0; w < 16; ++w) s += wsum[w];
        atomicAdd(out, s * ssc[2]);
    }
}

extern "C" void kernel_launch(void* const* d_in, const int* in_sizes, int n_in,
                              void* d_out, int out_size, void* d_ws, size_t ws_size,
                              hipStream_t stream) {
    const float* R     = (const float*)d_in[0];
    const int*   Z     = (const int*)d_in[1];
    const int*   idx   = (const int*)d_in[2];
    const float* a_exp = (const float*)d_in[3];
    const float* a_num = (const float*)d_in[4];
    const float* coef  = (const float*)d_in[5];
    const float* expo  = (const float*)d_in[6];
    const float* rs    = (const float*)d_in[7];

    float* out = (float*)d_out;
    float* wsf = (float*)d_ws;
    unsigned char* wsb = (unsigned char*)d_ws;

    const int nA = in_sizes[0] / 3;
    const int nE = in_sizes[2] / 2;
    const int* idx_i = idx;
    const int* idx_j = idx + nE;

    const int xyPad = (nA + 15) & ~15;
    const int half  = (nA + 1) >> 1;
    const int n4Pad = (half + 15) & ~15;
    unsigned char* XY = wsb + 512;
    unsigned char* N4 = XY + xyPad;
    s4* P8 = (s4*)(N4 + n4Pad);

    zbl_prep<<<1, 64, 0, stream>>>(a_exp, a_num, coef, expo, rs, wsf, out);
    atom_prep<<<(nA + 255) / 256, 256, 0, stream>>>(R, Z, XY, N4, P8, nA);

    // Device-constant path selection (same choice — same work — every call).
    int dev = 0;
    (void)hipGetDevice(&dev);
    int maxShm = 0;
    (void)hipDeviceGetAttribute(&maxShm, hipDeviceAttributeMaxSharedMemoryPerBlock, dev);
    const bool big = maxShm >= xyPad + 20000;   // dynamic table + ~17 KB static

    if (big) {
        (void)hipFuncSetAttribute((const void*)zbl_edges_big,
                                  hipFuncAttributeMaxDynamicSharedMemorySize, xyPad);
        zbl_edges_big<<<256, 1024, xyPad, stream>>>(XY, P8, R, idx_i, idx_j,
                                                    wsf, out, nE, nA);
    } else {
        zbl_edges_safe<<<512, 1024, n4Pad, stream>>>(N4, P8, R, idx_i, idx_j,
                                                     wsf, out, nE, nA);
    }
}

// Round 9
// 117.592 us; speedup vs baseline: 1.5664x; 1.0577x over previous
//
#include <hip/hip_runtime.h>
#include <math.h>

#define KE 14.3996f
#define R_MAX 6.0f

// P8 exact path: short4 {qx,qy,qz (step 1/512), Z} — validated R5-R8, absmax 0.0
#define PSCALE 512.0f
#define INV_PS2 (1.0f / (512.0f * 512.0f))

// ws float-index layout: [0] ae [1] 1/an [2] pre  [3..6] coeffs  [7..10] exps
// [16..79] powtab.  Byte offset 512+: XY, Z4, X4, P8 tables.
#define WS_POW_F 16

// Screens (all conservative-exact: discard ==> |delta|>=6 ==> cutoff==0):
//  XY byte: 4-bit bins/axis, width 2 over [-16,16], clamped.
//    discard iff |dbin|>=4 on x or y. Non-clamp: min |d| = 2(|dbin|-1) >= 6.
//    Clamp: end bins extend outward, gap only grows. Proof as R8.
//  Z4 nibble: same 4-bit width-2 code for z, packed 2 atoms/byte.
//  X4 nibble (safe path): same code for x only.

typedef short s4 __attribute__((ext_vector_type(4)));

__device__ __forceinline__ float softplus_f(float x) { return log1pf(expf(x)); }

__device__ __forceinline__ int bin2(float x) {
    int b = (int)floorf((x + 16.0f) * 0.5f);
    return min(max(b, 0), 15);
}

// Fused scalar prep + per-atom tables (one launch).
__global__ __launch_bounds__(256) void atom_prep(
        const float* __restrict__ R, const int* __restrict__ Z,
        const float* __restrict__ a_exp, const float* __restrict__ a_num,
        const float* __restrict__ coef, const float* __restrict__ expo,
        const float* __restrict__ rs,
        unsigned char* __restrict__ XY, unsigned char* __restrict__ Z4,
        unsigned char* __restrict__ X4, s4* __restrict__ P8,
        float* __restrict__ ws, float* __restrict__ out, int nA) {
    const int i = blockIdx.x * 256 + threadIdx.x;
    if (blockIdx.x == 0) {
        const int t = threadIdx.x;
        const float ae = softplus_f(a_exp[0]);
        if (t == 0) {
            ws[0] = ae;
            ws[1] = 1.0f / softplus_f(a_num[0]);
            ws[2] = 0.5f * KE * softplus_f(rs[0]);
            out[0] = 0.0f;   // d_out poisoned 0xAA before every timed call
        }
        if (t < 4) { ws[3 + t] = softplus_f(coef[t]); ws[7 + t] = softplus_f(expo[t]); }
        if (t < 64) ws[WS_POW_F + t] = (t > 0) ? expf(ae * logf((float)t)) : 0.0f;
    }
    if (i < nA) {
        const float x = R[3 * i], y = R[3 * i + 1], z = R[3 * i + 2];
        s4 v;
        v.x = (short)lrintf(x * PSCALE);
        v.y = (short)lrintf(y * PSCALE);
        v.z = (short)lrintf(z * PSCALE);
        v.w = (short)Z[i];
        P8[i] = v;
        XY[i] = (unsigned char)(bin2(x) | (bin2(y) << 4));
    }
    if ((i & 1) == 0 && i < nA) {        // even thread packs 2 atoms' nibbles
        unsigned int zb = (unsigned int)bin2(R[3 * i + 2]);
        unsigned int xb = (unsigned int)bin2(R[3 * i]);
        if (i + 1 < nA) {
            zb |= ((unsigned int)bin2(R[3 * (i + 1) + 2])) << 4;
            xb |= ((unsigned int)bin2(R[3 * (i + 1)])) << 4;
        }
        Z4[i >> 1] = (unsigned char)zb;
        X4[i >> 1] = (unsigned char)xb;
    }
}

// exact per-edge term (validated R5-R8: absmax 0.0)
__device__ __forceinline__ float edge_term(const s4* __restrict__ P8, int i, int j,
                                           const float* __restrict__ R,
                                           const float* __restrict__ spow,
                                           float inv_an,
                                           float c0, float c1, float c2, float c3,
                                           float e0, float e1, float e2, float e3) {
    const s4 pa = P8[i];
    const s4 pb = P8[j];
    const float dx = (float)(pb.x - pa.x);
    const float dy = (float)(pb.y - pa.y);
    const float dz = (float)(pb.z - pa.z);
    const float dr2 = (dx * dx + dy * dy + dz * dz) * INV_PS2;
    if (dr2 >= R_MAX * R_MAX) return 0.0f;   // screen conservative: exact re-check
    float dr;
    if (dr2 < 0.1225f) {
        // rare: 1/dr^2 sensitivity — recompute from exact fp32 R
        const float ax = R[3 * i], ay = R[3 * i + 1], az = R[3 * i + 2];
        const float bx = R[3 * j], by = R[3 * j + 1], bz = R[3 * j + 2];
        const float fx = bx - ax, fy = by - ay, fz = bz - az;
        dr = fmaxf(__fsqrt_rn(fx * fx + fy * fy + fz * fz), 0.02f);
    } else {
        dr = __fsqrt_rn(dr2);
    }
    const float ppa = spow[(int)pa.w] + spow[(int)pb.w];
    const float dist = dr * ppa * inv_an;
    const float f = c0 * __expf(-e0 * dist) + c1 * __expf(-e1 * dist)
                  + c2 * __expf(-e2 * dist) + c3 * __expf(-e3 * dist);
    const float cut = 0.5f * (__cosf((float)M_PI / R_MAX * dr) + 1.0f);
    return (float)pa.w * (float)pb.w / dr * f * cut;
}

#define QCAP 96   // wave-queue capacity; pop threshold 32: count<=31 -> +64 -> <=95

#define EDGE_BODY(SCREEN_KEEP)                                                  \
    const float inv_an = ssc[1];                                                \
    const float c0 = ssc[3], c1 = ssc[4], c2 = ssc[5], c3 = ssc[6];             \
    const float e0 = ssc[7], e1 = ssc[8], e2 = ssc[9], e3 = ssc[10];            \
    float local = 0.0f;                                                         \
    int count = 0;                                                              \
    const int nG = (nE + 63) >> 6;                                              \
    const int wpb = blockDim.x >> 6;                                            \
    const int nW = gridDim.x * wpb;                                             \
    for (int g = blockIdx.x * wpb + wv; g < nG; g += nW) {                      \
        const int e = (g << 6) + lane;                                          \
        int i = 0, j = 0;                                                       \
        bool keep = false;                                                      \
        if (e < nE) {                                                           \
            i = idx_i[e];                                                       \
            j = idx_j[e];                                                       \
            keep = (SCREEN_KEEP) && (i != j);                                   \
        }                                                                       \
        const unsigned long long m = __ballot(keep);                            \
        if (keep) {                                                             \
            const int pos = count + __popcll(m & ((1ull << lane) - 1));         \
            buf[wv][pos] = ((unsigned long long)(unsigned int)i << 32)          \
                           | (unsigned int)j;                                   \
        }                                                                       \
        count += __popcll(m);                                                   \
        if (count >= 32) {       /* pop dense batch, no barriers */             \
            const int k = (count < 64) ? count : 64;                            \
            count -= k;                                                         \
            if (lane < k) {                                                     \
                const unsigned long long p = buf[wv][count + lane];             \
                local += edge_term(P8, (int)(p >> 32), (int)(p & 0xffffffffu),  \
                                   R, spow, inv_an, c0, c1, c2, c3, e0, e1, e2, e3); \
            }                                                                   \
        }                                                                       \
    }                                                                           \
    while (count > 0) {          /* drain */                                    \
        const int k = (count < 64) ? count : 64;                                \
        count -= k;                                                             \
        if (lane < k) {                                                         \
            const unsigned long long p = buf[wv][count + lane];                 \
            local += edge_term(P8, (int)(p >> 32), (int)(p & 0xffffffffu),      \
                               R, spow, inv_an, c0, c1, c2, c3, e0, e1, e2, e3); \
        }                                                                       \
    }                                                                           \
    for (int off = 32; off > 0; off >>= 1) local += __shfl_down(local, off);    \
    if (lane == 0) wsum[wv] = local;                                            \
    __syncthreads();                                                            \
    if (threadIdx.x == 0) {                                                     \
        float s = 0.0f;                                                         \
        for (int w = 0; w < (int)(blockDim.x >> 6); ++w) s += wsum[w];          \
        atomicAdd(out, s * ssc[2]);                                             \
    }

// BIG: XY byte (100 KB) + Z nibble (50 KB) in dynamic LDS; keep ~5.5%.
__global__ __launch_bounds__(1024) void zbl_big(
        const unsigned char* __restrict__ XY, const unsigned char* __restrict__ Z4,
        const s4* __restrict__ P8, const float* __restrict__ R,
        const int* __restrict__ idx_i, const int* __restrict__ idx_j,
        const float* __restrict__ ws, float* __restrict__ out, int nE, int nA) {
    extern __shared__ unsigned char lds[];
    __shared__ unsigned long long buf[16][QCAP];
    __shared__ float spow[64];
    __shared__ float ssc[11];
    __shared__ float wsum[16];
    const int tid = threadIdx.x, lane = tid & 63, wv = tid >> 6;
    const int xyPad = (nA + 15) & ~15;
    const int z4Pad = (((nA + 1) >> 1) + 15) & ~15;
    for (int off = tid * 16; off < xyPad; off += 1024 * 16)
        *(int4*)(lds + off) = *(const int4*)(XY + off);
    unsigned char* ldsZ = lds + xyPad;
    for (int off = tid * 16; off < z4Pad; off += 1024 * 16)
        *(int4*)(ldsZ + off) = *(const int4*)(Z4 + off);
    if (tid < 64) spow[tid] = ws[WS_POW_F + tid];
    if (tid < 11) ssc[tid] = ws[tid];
    __syncthreads();

    EDGE_BODY((
        [&]() -> bool {
            const unsigned int ci = lds[i], cj = lds[j];
            const unsigned int zi = (ldsZ[i >> 1] >> ((i & 1) * 4)) & 15u;
            const unsigned int zj = (ldsZ[j >> 1] >> ((j & 1) * 4)) & 15u;
            return (abs((int)(ci & 15u) - (int)(cj & 15u)) <= 3)
                && (abs((int)(ci >> 4) - (int)(cj >> 4)) <= 3)
                && (abs((int)zi - (int)zj) <= 3);
        }()))
}

// SAFE (<=64 KB): 4-bit x-axis nibble table (50 KB); keep ~38%.
__global__ __launch_bounds__(1024) void zbl_safe(
        const unsigned char* __restrict__ X4,
        const s4* __restrict__ P8, const float* __restrict__ R,
        const int* __restrict__ idx_i, const int* __restrict__ idx_j,
        const float* __restrict__ ws, float* __restrict__ out, int nE, int nA) {
    extern __shared__ unsigned char lds[];
    __shared__ unsigned long long buf[16][QCAP];
    __shared__ float spow[64];
    __shared__ float ssc[11];
    __shared__ float wsum[16];
    const int tid = threadIdx.x, lane = tid & 63, wv = tid >> 6;
    const int x4Pad = (((nA + 1) >> 1) + 15) & ~15;
    for (int off = tid * 16; off < x4Pad; off += 1024 * 16)
        *(int4*)(lds + off) = *(const int4*)(X4 + off);
    if (tid < 64) spow[tid] = ws[WS_POW_F + tid];
    if (tid < 11) ssc[tid] = ws[tid];
    __syncthreads();

    EDGE_BODY((
        [&]() -> bool {
            const unsigned int bi = (lds[i >> 1] >> ((i & 1) * 4)) & 15u;
            const unsigned int bj = (lds[j >> 1] >> ((j & 1) * 4)) & 15u;
            return abs((int)bi - (int)bj) <= 3;
        }()))
}

extern "C" void kernel_launch(void* const* d_in, const int* in_sizes, int n_in,
                              void* d_out, int out_size, void* d_ws, size_t ws_size,
                              hipStream_t stream) {
    const float* R     = (const float*)d_in[0];
    const int*   Z     = (const int*)d_in[1];
    const int*   idx   = (const int*)d_in[2];
    const float* a_exp = (const float*)d_in[3];
    const float* a_num = (const float*)d_in[4];
    const float* coef  = (const float*)d_in[5];
    const float* expo  = (const float*)d_in[6];
    const float* rs    = (const float*)d_in[7];

    float* out = (float*)d_out;
    float* wsf = (float*)d_ws;
    unsigned char* wsb = (unsigned char*)d_ws;

    const int nA = in_sizes[0] / 3;
    const int nE = in_sizes[2] / 2;
    const int* idx_i = idx;
    const int* idx_j = idx + nE;

    const int xyPad = (nA + 15) & ~15;
    const int nibPad = (((nA + 1) >> 1) + 15) & ~15;
    unsigned char* XY = wsb + 512;
    unsigned char* Z4 = XY + xyPad;
    unsigned char* X4 = Z4 + nibPad;
    s4* P8 = (s4*)(X4 + nibPad);

    atom_prep<<<(nA + 255) / 256, 256, 0, stream>>>(R, Z, a_exp, a_num, coef,
                                                    expo, rs, XY, Z4, X4, P8,
                                                    wsf, out, nA);

    // Deterministic per-device path selection (same work every call).
    const int dynBig = xyPad + nibPad;          // 150 KB for nA=100K
    int dev = 0;
    (void)hipGetDevice(&dev);
    int maxShm = 0;
    (void)hipDeviceGetAttribute(&maxShm, hipDeviceAttributeMaxSharedMemoryPerBlock, dev);
    hipFuncAttributes fa{};
    (void)hipFuncGetAttributes(&fa, (const void*)zbl_big);
    const int staticLds = 16 * QCAP * 8 + 256 + 48 + 64 + 64;   // ~12.7 KB
    const bool big = (maxShm >= dynBig + staticLds) ||
                     (fa.maxDynamicSharedSizeBytes >= dynBig);

    if (big) {
        (void)hipFuncSetAttribute((const void*)zbl_big,
                                  hipFuncAttributeMaxDynamicSharedMemorySize, dynBig);
        zbl_big<<<256, 1024, dynBig, stream>>>(XY, Z4, P8, R, idx_i, idx_j,
                                               wsf, out, nE, nA);
    } else {
        zbl_safe<<<512, 1024, nibPad, stream>>>(X4, P8, R, idx_i, idx_j,
                                                wsf, out, nE, nA);
    }
}

// Round 10
// 113.506 us; speedup vs baseline: 1.6228x; 1.0360x over previous
//
#include <hip/hip_runtime.h>
#include <math.h>

#define KE 14.3996f
#define R_MAX 6.0f

// P8 exact path: short4 {qx,qy,qz (step 1/512), Z} — validated R5-R9, absmax 0.0
#define PSCALE 512.0f
#define INV_PS2 (1.0f / (512.0f * 512.0f))

// ws float-index layout: [0] ae [1] 1/an [2] pre  [3..6] coeffs  [7..10] exps
// [16..79] powtab.  Byte offset 512+: XY, Z4, X4, P8 tables.
#define WS_POW_F 16

// Screens (conservative-exact: discard ==> |delta|>=6 ==> cutoff==0):
//  XY byte: 4-bit bins/axis, width 2 over [-16,16], clamped.
//    discard iff |dbin|>=4 on x or y (non-clamp min gap 2(|db|-1)>=6; clamp grows it).
//  Z4 / X4 nibble: same 4-bit width-2 code, packed 2 atoms/byte.

typedef short s4 __attribute__((ext_vector_type(4)));

__device__ __forceinline__ float softplus_f(float x) { return log1pf(expf(x)); }

__device__ __forceinline__ int bin2(float x) {
    int b = (int)floorf((x + 16.0f) * 0.5f);
    return min(max(b, 0), 15);
}

// Fused scalar prep + per-atom tables (one launch).
__global__ __launch_bounds__(256) void atom_prep(
        const float* __restrict__ R, const int* __restrict__ Z,
        const float* __restrict__ a_exp, const float* __restrict__ a_num,
        const float* __restrict__ coef, const float* __restrict__ expo,
        const float* __restrict__ rs,
        unsigned char* __restrict__ XY, unsigned char* __restrict__ Z4,
        unsigned char* __restrict__ X4, s4* __restrict__ P8,
        float* __restrict__ ws, float* __restrict__ out, int nA) {
    const int i = blockIdx.x * 256 + threadIdx.x;
    if (blockIdx.x == 0) {
        const int t = threadIdx.x;
        const float ae = softplus_f(a_exp[0]);
        if (t == 0) {
            ws[0] = ae;
            ws[1] = 1.0f / softplus_f(a_num[0]);
            ws[2] = 0.5f * KE * softplus_f(rs[0]);
            out[0] = 0.0f;   // d_out poisoned 0xAA before every timed call
        }
        if (t < 4) { ws[3 + t] = softplus_f(coef[t]); ws[7 + t] = softplus_f(expo[t]); }
        if (t < 64) ws[WS_POW_F + t] = (t > 0) ? expf(ae * logf((float)t)) : 0.0f;
    }
    if (i < nA) {
        const float x = R[3 * i], y = R[3 * i + 1], z = R[3 * i + 2];
        s4 v;
        v.x = (short)lrintf(x * PSCALE);
        v.y = (short)lrintf(y * PSCALE);
        v.z = (short)lrintf(z * PSCALE);
        v.w = (short)Z[i];
        P8[i] = v;
        XY[i] = (unsigned char)(bin2(x) | (bin2(y) << 4));
    }
    if ((i & 1) == 0 && i < nA) {        // even thread packs 2 atoms' nibbles
        unsigned int zb = (unsigned int)bin2(R[3 * i + 2]);
        unsigned int xb = (unsigned int)bin2(R[3 * i]);
        if (i + 1 < nA) {
            zb |= ((unsigned int)bin2(R[3 * (i + 1) + 2])) << 4;
            xb |= ((unsigned int)bin2(R[3 * (i + 1)])) << 4;
        }
        Z4[i >> 1] = (unsigned char)zb;
        X4[i >> 1] = (unsigned char)xb;
    }
}

// exact per-edge term (validated R5-R9: absmax 0.0)
__device__ __forceinline__ float edge_term(const s4* __restrict__ P8, int i, int j,
                                           const float* __restrict__ R,
                                           const float* __restrict__ spow,
                                           float inv_an,
                                           float c0, float c1, float c2, float c3,
                                           float e0, float e1, float e2, float e3) {
    const s4 pa = P8[i];
    const s4 pb = P8[j];
    const float dx = (float)(pb.x - pa.x);
    const float dy = (float)(pb.y - pa.y);
    const float dz = (float)(pb.z - pa.z);
    const float dr2 = (dx * dx + dy * dy + dz * dz) * INV_PS2;
    if (dr2 >= R_MAX * R_MAX) return 0.0f;   // screen conservative: exact re-check
    float dr;
    if (dr2 < 0.1225f) {
        // rare: 1/dr^2 sensitivity — recompute from exact fp32 R
        const float ax = R[3 * i], ay = R[3 * i + 1], az = R[3 * i + 2];
        const float bx = R[3 * j], by = R[3 * j + 1], bz = R[3 * j + 2];
        const float fx = bx - ax, fy = by - ay, fz = bz - az;
        dr = fmaxf(__fsqrt_rn(fx * fx + fy * fy + fz * fz), 0.02f);
    } else {
        dr = __fsqrt_rn(dr2);
    }
    const float ppa = spow[(int)pa.w] + spow[(int)pb.w];
    const float dist = dr * ppa * inv_an;
    const float f = c0 * __expf(-e0 * dist) + c1 * __expf(-e1 * dist)
                  + c2 * __expf(-e2 * dist) + c3 * __expf(-e3 * dist);
    const float cut = 0.5f * (__cosf((float)M_PI / R_MAX * dr) + 1.0f);
    return (float)pa.w * (float)pb.w / dr * f * cut;
}

#define QCAP 96   // count<=31 before each push; push<=64 -> peak<=95

#define PUSH_POP(k_, iv, jv)                                                    \
    {                                                                           \
        const bool _k = (k_);                                                   \
        const unsigned long long _m = __ballot(_k);                             \
        if (_k) {                                                               \
            const int _pos = count + __popcll(_m & ((1ull << lane) - 1));       \
            buf[wv][_pos] = ((unsigned long long)(unsigned int)(iv) << 32)      \
                            | (unsigned int)(jv);                               \
        }                                                                       \
        count += __popcll(_m);                                                  \
        if (count >= 32) {       /* pop dense batch, no barriers */             \
            const int _kk = (count < 64) ? count : 64;                          \
            count -= _kk;                                                       \
            if (lane < _kk) {                                                   \
                const unsigned long long _p = buf[wv][count + lane];            \
                local += edge_term(P8, (int)(_p >> 32), (int)(_p & 0xffffffffu),\
                                   R, spow, inv_an, c0,c1,c2,c3, e0,e1,e2,e3);  \
            }                                                                   \
        }                                                                       \
    }

// 2 edges/lane per iteration: int2 idx loads (8B coalesced), half the loop
// iterations of R9, interleaved pop-checks keep QCAP at 96.
#define EDGE_BODY                                                               \
    const float inv_an = ssc[1];                                                \
    const float c0 = ssc[3], c1 = ssc[4], c2 = ssc[5], c3 = ssc[6];             \
    const float e0 = ssc[7], e1 = ssc[8], e2 = ssc[9], e3 = ssc[10];            \
    float local = 0.0f;                                                         \
    int count = 0;                                                              \
    const int wpb = blockDim.x >> 6;                                            \
    const int nW = gridDim.x * wpb;                                             \
    const int nG = (nE + 127) >> 7;                                             \
    for (int g = blockIdx.x * wpb + wv; g < nG; g += nW) {                      \
        const int base = (g << 7) + (lane << 1);                                \
        int2 ii, jj;                                                            \
        ii.x = ii.y = jj.x = jj.y = 0;                                          \
        bool v0 = false, v1 = false;                                            \
        if (base + 1 < nE) {                                                    \
            ii = *(const int2*)(idx_i + base);                                  \
            jj = *(const int2*)(idx_j + base);                                  \
            v0 = v1 = true;                                                     \
        } else if (base < nE) {                                                 \
            ii.x = idx_i[base]; jj.x = idx_j[base]; v0 = true;                  \
        }                                                                       \
        const bool k0 = v0 && keepf(ii.x, jj.x) && (ii.x != jj.x);              \
        const bool k1 = v1 && keepf(ii.y, jj.y) && (ii.y != jj.y);              \
        PUSH_POP(k0, ii.x, jj.x)                                                \
        PUSH_POP(k1, ii.y, jj.y)                                                \
    }                                                                           \
    while (count > 0) {          /* drain */                                    \
        const int k = (count < 64) ? count : 64;                                \
        count -= k;                                                             \
        if (lane < k) {                                                         \
            const unsigned long long p = buf[wv][count + lane];                 \
            local += edge_term(P8, (int)(p >> 32), (int)(p & 0xffffffffu),      \
                               R, spow, inv_an, c0,c1,c2,c3, e0,e1,e2,e3);      \
        }                                                                       \
    }                                                                           \
    for (int off = 32; off > 0; off >>= 1) local += __shfl_down(local, off);    \
    if (lane == 0) wsum[wv] = local;                                            \
    __syncthreads();                                                            \
    if (threadIdx.x == 0) {                                                     \
        float s = 0.0f;                                                         \
        for (int w = 0; w < (int)(blockDim.x >> 6); ++w) s += wsum[w];          \
        atomicAdd(out, s * ssc[2]);                                             \
    }

// BIG: XY byte (100 KB) + Z nibble (50 KB) in dynamic LDS; keep ~5.5%.
__global__ __launch_bounds__(1024) void zbl_big(
        const unsigned char* __restrict__ XY, const unsigned char* __restrict__ Z4,
        const s4* __restrict__ P8, const float* __restrict__ R,
        const int* __restrict__ idx_i, const int* __restrict__ idx_j,
        const float* __restrict__ ws, float* __restrict__ out, int nE, int nA) {
    extern __shared__ unsigned char lds[];
    __shared__ unsigned long long buf[16][QCAP];
    __shared__ float spow[64];
    __shared__ float ssc[11];
    __shared__ float wsum[16];
    const int tid = threadIdx.x, lane = tid & 63, wv = tid >> 6;
    const int xyPad = (nA + 15) & ~15;
    const int z4Pad = (((nA + 1) >> 1) + 15) & ~15;
    for (int off = tid * 16; off < xyPad; off += 1024 * 16)
        *(int4*)(lds + off) = *(const int4*)(XY + off);
    unsigned char* ldsZ = lds + xyPad;
    for (int off = tid * 16; off < z4Pad; off += 1024 * 16)
        *(int4*)(ldsZ + off) = *(const int4*)(Z4 + off);
    if (tid < 64) spow[tid] = ws[WS_POW_F + tid];
    if (tid < 11) ssc[tid] = ws[tid];
    __syncthreads();

    auto keepf = [&](int i, int j) -> bool {
        const unsigned int ci = lds[i], cj = lds[j];
        const unsigned int zi = (ldsZ[i >> 1] >> ((i & 1) * 4)) & 15u;
        const unsigned int zj = (ldsZ[j >> 1] >> ((j & 1) * 4)) & 15u;
        return (abs((int)(ci & 15u) - (int)(cj & 15u)) <= 3)
            && (abs((int)(ci >> 4) - (int)(cj >> 4)) <= 3)
            && (abs((int)zi - (int)zj) <= 3);
    };
    EDGE_BODY
}

// SAFE (<=64 KB): 4-bit x-axis nibble table (50 KB); keep ~38%.
__global__ __launch_bounds__(1024) void zbl_safe(
        const unsigned char* __restrict__ X4,
        const s4* __restrict__ P8, const float* __restrict__ R,
        const int* __restrict__ idx_i, const int* __restrict__ idx_j,
        const float* __restrict__ ws, float* __restrict__ out, int nE, int nA) {
    extern __shared__ unsigned char lds[];
    __shared__ unsigned long long buf[16][QCAP];
    __shared__ float spow[64];
    __shared__ float ssc[11];
    __shared__ float wsum[16];
    const int tid = threadIdx.x, lane = tid & 63, wv = tid >> 6;
    const int x4Pad = (((nA + 1) >> 1) + 15) & ~15;
    for (int off = tid * 16; off < x4Pad; off += 1024 * 16)
        *(int4*)(lds + off) = *(const int4*)(X4 + off);
    if (tid < 64) spow[tid] = ws[WS_POW_F + tid];
    if (tid < 11) ssc[tid] = ws[tid];
    __syncthreads();

    auto keepf = [&](int i, int j) -> bool {
        const unsigned int bi = (lds[i >> 1] >> ((i & 1) * 4)) & 15u;
        const unsigned int bj = (lds[j >> 1] >> ((j & 1) * 4)) & 15u;
        return abs((int)bi - (int)bj) <= 3;
    };
    EDGE_BODY
}

extern "C" void kernel_launch(void* const* d_in, const int* in_sizes, int n_in,
                              void* d_out, int out_size, void* d_ws, size_t ws_size,
                              hipStream_t stream) {
    const float* R     = (const float*)d_in[0];
    const int*   Z     = (const int*)d_in[1];
    const int*   idx   = (const int*)d_in[2];
    const float* a_exp = (const float*)d_in[3];
    const float* a_num = (const float*)d_in[4];
    const float* coef  = (const float*)d_in[5];
    const float* expo  = (const float*)d_in[6];
    const float* rs    = (const float*)d_in[7];

    float* out = (float*)d_out;
    float* wsf = (float*)d_ws;
    unsigned char* wsb = (unsigned char*)d_ws;

    const int nA = in_sizes[0] / 3;
    const int nE = in_sizes[2] / 2;
    const int* idx_i = idx;
    const int* idx_j = idx + nE;

    const int xyPad = (nA + 15) & ~15;
    const int nibPad = (((nA + 1) >> 1) + 15) & ~15;
    unsigned char* XY = wsb + 512;
    unsigned char* Z4 = XY + xyPad;
    unsigned char* X4 = Z4 + nibPad;
    s4* P8 = (s4*)(X4 + nibPad);

    atom_prep<<<(nA + 255) / 256, 256, 0, stream>>>(R, Z, a_exp, a_num, coef,
                                                    expo, rs, XY, Z4, X4, P8,
                                                    wsf, out, nA);

    // Deterministic per-device path selection (same work every call).
    const int dynBig = xyPad + nibPad;          // 150 KB for nA=100K
    int dev = 0;
    (void)hipGetDevice(&dev);
    int maxShm = 0;
    (void)hipDeviceGetAttribute(&maxShm, hipDeviceAttributeMaxSharedMemoryPerBlock, dev);
    hipFuncAttributes fa{};
    (void)hipFuncGetAttributes(&fa, (const void*)zbl_big);
    const int staticLds = 16 * QCAP * 8 + 256 + 48 + 64 + 64;   // ~12.7 KB
    const bool big = (maxShm >= dynBig + staticLds) ||
                     (fa.maxDynamicSharedSizeBytes >= dynBig);

    if (big) {
        (void)hipFuncSetAttribute((const void*)zbl_big,
                                  hipFuncAttributeMaxDynamicSharedMemorySize, dynBig);
        zbl_big<<<256, 1024, dynBig, stream>>>(XY, Z4, P8, R, idx_i, idx_j,
                                               wsf, out, nE, nA);
    } else {
        zbl_safe<<<512, 1024, nibPad, stream>>>(X4, P8, R, idx_i, idx_j,
                                                wsf, out, nE, nA);
    }
}

// Round 11
// 110.569 us; speedup vs baseline: 1.6659x; 1.0266x over previous
//
#include <hip/hip_runtime.h>
#include <math.h>

#define KE 14.3996f
#define R_MAX 6.0f

// P8 exact path: short4 {qx,qy,qz (step 1/512), Z} — validated R5-R10, absmax 0.0
#define PSCALE 512.0f
#define INV_PS2 (1.0f / (512.0f * 512.0f))

// ws float-index layout: [0] ae [1] 1/an [2] pre  [3..6] coeffs  [7..10] exps
// [16..79] powtab.  Byte offset 512+: XY, Z4, X4, P8 tables.
#define WS_POW_F 16

// Screens (conservative-exact: discard ==> |delta|>=6 ==> cutoff==0):
//  XY byte: 4-bit bins/axis, width 2 over [-16,16], clamped.
//    discard iff |dbin|>=4 on x or y (non-clamp min gap 2(|db|-1)>=6; clamp grows it).
//  Z4 / X4 nibble: same 4-bit width-2 code, packed 2 atoms/byte.

typedef short s4 __attribute__((ext_vector_type(4)));

__device__ __forceinline__ float softplus_f(float x) { return log1pf(expf(x)); }

__device__ __forceinline__ int bin2(float x) {
    int b = (int)floorf((x + 16.0f) * 0.5f);
    return min(max(b, 0), 15);
}

// Fused scalar prep + per-atom tables (one launch).
__global__ __launch_bounds__(256) void atom_prep(
        const float* __restrict__ R, const int* __restrict__ Z,
        const float* __restrict__ a_exp, const float* __restrict__ a_num,
        const float* __restrict__ coef, const float* __restrict__ expo,
        const float* __restrict__ rs,
        unsigned char* __restrict__ XY, unsigned char* __restrict__ Z4,
        unsigned char* __restrict__ X4, s4* __restrict__ P8,
        float* __restrict__ ws, float* __restrict__ out, int nA) {
    const int i = blockIdx.x * 256 + threadIdx.x;
    if (blockIdx.x == 0) {
        const int t = threadIdx.x;
        const float ae = softplus_f(a_exp[0]);
        if (t == 0) {
            ws[0] = ae;
            ws[1] = 1.0f / softplus_f(a_num[0]);
            ws[2] = 0.5f * KE * softplus_f(rs[0]);
            out[0] = 0.0f;   // d_out poisoned 0xAA before every timed call
        }
        if (t < 4) { ws[3 + t] = softplus_f(coef[t]); ws[7 + t] = softplus_f(expo[t]); }
        if (t < 64) ws[WS_POW_F + t] = (t > 0) ? expf(ae * logf((float)t)) : 0.0f;
    }
    if (i < nA) {
        const float x = R[3 * i], y = R[3 * i + 1], z = R[3 * i + 2];
        s4 v;
        v.x = (short)lrintf(x * PSCALE);
        v.y = (short)lrintf(y * PSCALE);
        v.z = (short)lrintf(z * PSCALE);
        v.w = (short)Z[i];
        P8[i] = v;
        XY[i] = (unsigned char)(bin2(x) | (bin2(y) << 4));
    }
    if ((i & 1) == 0 && i < nA) {        // even thread packs 2 atoms' nibbles
        unsigned int zb = (unsigned int)bin2(R[3 * i + 2]);
        unsigned int xb = (unsigned int)bin2(R[3 * i]);
        if (i + 1 < nA) {
            zb |= ((unsigned int)bin2(R[3 * (i + 1) + 2])) << 4;
            xb |= ((unsigned int)bin2(R[3 * (i + 1)])) << 4;
        }
        Z4[i >> 1] = (unsigned char)zb;
        X4[i >> 1] = (unsigned char)xb;
    }
}

// exact per-edge term (validated R5-R10: absmax 0.0)
__device__ __forceinline__ float edge_term(const s4* __restrict__ P8, int i, int j,
                                           const float* __restrict__ R,
                                           const float* __restrict__ spow,
                                           float inv_an,
                                           float c0, float c1, float c2, float c3,
                                           float e0, float e1, float e2, float e3) {
    const s4 pa = P8[i];
    const s4 pb = P8[j];
    const float dx = (float)(pb.x - pa.x);
    const float dy = (float)(pb.y - pa.y);
    const float dz = (float)(pb.z - pa.z);
    const float dr2 = (dx * dx + dy * dy + dz * dz) * INV_PS2;
    if (dr2 >= R_MAX * R_MAX) return 0.0f;   // screen conservative: exact re-check
    float dr;
    if (dr2 < 0.1225f) {
        // rare: 1/dr^2 sensitivity — recompute from exact fp32 R
        const float ax = R[3 * i], ay = R[3 * i + 1], az = R[3 * i + 2];
        const float bx = R[3 * j], by = R[3 * j + 1], bz = R[3 * j + 2];
        const float fx = bx - ax, fy = by - ay, fz = bz - az;
        dr = fmaxf(__fsqrt_rn(fx * fx + fy * fy + fz * fz), 0.02f);
    } else {
        dr = __fsqrt_rn(dr2);
    }
    const float ppa = spow[(int)pa.w] + spow[(int)pb.w];
    const float dist = dr * ppa * inv_an;
    const float f = c0 * __expf(-e0 * dist) + c1 * __expf(-e1 * dist)
                  + c2 * __expf(-e2 * dist) + c3 * __expf(-e3 * dist);
    const float cut = 0.5f * (__cosf((float)M_PI / R_MAX * dr) + 1.0f);
    return (float)pa.w * (float)pb.w / dr * f * cut;
}

#define QCAP 96   // count<=31 before each push; push<=64 -> peak<=95

#define PUSH_POP(k_, iv, jv)                                                    \
    {                                                                           \
        const bool _k = (k_);                                                   \
        const unsigned long long _m = __ballot(_k);                             \
        if (_k) {                                                               \
            const int _pos = count + __popcll(_m & ((1ull << lane) - 1));       \
            buf[wv][_pos] = ((unsigned long long)(unsigned int)(iv) << 32)      \
                            | (unsigned int)(jv);                               \
        }                                                                       \
        count += __popcll(_m);                                                  \
        if (count >= 32) {       /* pop dense batch, no barriers */             \
            const int _kk = (count < 64) ? count : 64;                          \
            count -= _kk;                                                       \
            if (lane < _kk) {                                                   \
                const unsigned long long _p = buf[wv][count + lane];            \
                local += edge_term(P8, (int)(_p >> 32), (int)(_p & 0xffffffffu),\
                                   R, spow, inv_an, c0,c1,c2,c3, e0,e1,e2,e3);  \
            }                                                                   \
        }                                                                       \
    }

// 4 edges/lane per iteration: int4 idx loads (16B coalesced — the G13 sweet
// spot), quarter of R9's loop iterations, pop-check after each push keeps
// the QCAP=96 invariant (count<=31 before push, peak<=95).
#define EDGE_BODY                                                               \
    const float inv_an = ssc[1];                                                \
    const float c0 = ssc[3], c1 = ssc[4], c2 = ssc[5], c3 = ssc[6];             \
    const float e0 = ssc[7], e1 = ssc[8], e2 = ssc[9], e3 = ssc[10];            \
    float local = 0.0f;                                                         \
    int count = 0;                                                              \
    const int wpb = blockDim.x >> 6;                                            \
    const int nW = gridDim.x * wpb;                                             \
    const int nG = (nE + 255) >> 8;                                             \
    for (int g = blockIdx.x * wpb + wv; g < nG; g += nW) {                      \
        const int base = (g << 8) + (lane << 2);                                \
        int4 ii, jj;                                                            \
        bool v0 = false, v1 = false, v2 = false, v3 = false;                    \
        if (base + 3 < nE) {                                                    \
            ii = *(const int4*)(idx_i + base);                                  \
            jj = *(const int4*)(idx_j + base);                                  \
            v0 = v1 = v2 = v3 = true;                                           \
        } else {                                                                \
            ii.x = ii.y = ii.z = ii.w = 0;                                      \
            jj.x = jj.y = jj.z = jj.w = 0;                                      \
            if (base < nE)     { ii.x = idx_i[base];     jj.x = idx_j[base];     v0 = true; } \
            if (base + 1 < nE) { ii.y = idx_i[base + 1]; jj.y = idx_j[base + 1]; v1 = true; } \
            if (base + 2 < nE) { ii.z = idx_i[base + 2]; jj.z = idx_j[base + 2]; v2 = true; } \
        }                                                                       \
        const bool k0 = v0 && keepf(ii.x, jj.x) && (ii.x != jj.x);              \
        const bool k1 = v1 && keepf(ii.y, jj.y) && (ii.y != jj.y);              \
        const bool k2 = v2 && keepf(ii.z, jj.z) && (ii.z != jj.z);              \
        const bool k3 = v3 && keepf(ii.w, jj.w) && (ii.w != jj.w);              \
        PUSH_POP(k0, ii.x, jj.x)                                                \
        PUSH_POP(k1, ii.y, jj.y)                                                \
        PUSH_POP(k2, ii.z, jj.z)                                                \
        PUSH_POP(k3, ii.w, jj.w)                                                \
    }                                                                           \
    while (count > 0) {          /* drain */                                    \
        const int k = (count < 64) ? count : 64;                                \
        count -= k;                                                             \
        if (lane < k) {                                                         \
            const unsigned long long p = buf[wv][count + lane];                 \
            local += edge_term(P8, (int)(p >> 32), (int)(p & 0xffffffffu),      \
                               R, spow, inv_an, c0,c1,c2,c3, e0,e1,e2,e3);      \
        }                                                                       \
    }                                                                           \
    for (int off = 32; off > 0; off >>= 1) local += __shfl_down(local, off);    \
    if (lane == 0) wsum[wv] = local;                                            \
    __syncthreads();                                                            \
    if (threadIdx.x == 0) {                                                     \
        float s = 0.0f;                                                         \
        for (int w = 0; w < (int)(blockDim.x >> 6); ++w) s += wsum[w];          \
        atomicAdd(out, s * ssc[2]);                                             \
    }

// BIG: XY byte (100 KB) + Z nibble (50 KB) in dynamic LDS; keep ~5.5%.
__global__ __launch_bounds__(1024) void zbl_big(
        const unsigned char* __restrict__ XY, const unsigned char* __restrict__ Z4,
        const s4* __restrict__ P8, const float* __restrict__ R,
        const int* __restrict__ idx_i, const int* __restrict__ idx_j,
        const float* __restrict__ ws, float* __restrict__ out, int nE, int nA) {
    extern __shared__ unsigned char lds[];
    __shared__ unsigned long long buf[16][QCAP];
    __shared__ float spow[64];
    __shared__ float ssc[11];
    __shared__ float wsum[16];
    const int tid = threadIdx.x, lane = tid & 63, wv = tid >> 6;
    const int xyPad = (nA + 15) & ~15;
    const int z4Pad = (((nA + 1) >> 1) + 15) & ~15;
    for (int off = tid * 16; off < xyPad; off += 1024 * 16)
        *(int4*)(lds + off) = *(const int4*)(XY + off);
    unsigned char* ldsZ = lds + xyPad;
    for (int off = tid * 16; off < z4Pad; off += 1024 * 16)
        *(int4*)(ldsZ + off) = *(const int4*)(Z4 + off);
    if (tid < 64) spow[tid] = ws[WS_POW_F + tid];
    if (tid < 11) ssc[tid] = ws[tid];
    __syncthreads();

    auto keepf = [&](int i, int j) -> bool {
        const unsigned int ci = lds[i], cj = lds[j];
        const unsigned int zi = (ldsZ[i >> 1] >> ((i & 1) * 4)) & 15u;
        const unsigned int zj = (ldsZ[j >> 1] >> ((j & 1) * 4)) & 15u;
        return (abs((int)(ci & 15u) - (int)(cj & 15u)) <= 3)
            && (abs((int)(ci >> 4) - (int)(cj >> 4)) <= 3)
            && (abs((int)zi - (int)zj) <= 3);
    };
    EDGE_BODY
}

// SAFE (<=64 KB): 4-bit x-axis nibble table (50 KB); keep ~38%.
__global__ __launch_bounds__(1024) void zbl_safe(
        const unsigned char* __restrict__ X4,
        const s4* __restrict__ P8, const float* __restrict__ R,
        const int* __restrict__ idx_i, const int* __restrict__ idx_j,
        const float* __restrict__ ws, float* __restrict__ out, int nE, int nA) {
    extern __shared__ unsigned char lds[];
    __shared__ unsigned long long buf[16][QCAP];
    __shared__ float spow[64];
    __shared__ float ssc[11];
    __shared__ float wsum[16];
    const int tid = threadIdx.x, lane = tid & 63, wv = tid >> 6;
    const int x4Pad = (((nA + 1) >> 1) + 15) & ~15;
    for (int off = tid * 16; off < x4Pad; off += 1024 * 16)
        *(int4*)(lds + off) = *(const int4*)(X4 + off);
    if (tid < 64) spow[tid] = ws[WS_POW_F + tid];
    if (tid < 11) ssc[tid] = ws[tid];
    __syncthreads();

    auto keepf = [&](int i, int j) -> bool {
        const unsigned int bi = (lds[i >> 1] >> ((i & 1) * 4)) & 15u;
        const unsigned int bj = (lds[j >> 1] >> ((j & 1) * 4)) & 15u;
        return abs((int)bi - (int)bj) <= 3;
    };
    EDGE_BODY
}

extern "C" void kernel_launch(void* const* d_in, const int* in_sizes, int n_in,
                              void* d_out, int out_size, void* d_ws, size_t ws_size,
                              hipStream_t stream) {
    const float* R     = (const float*)d_in[0];
    const int*   Z     = (const int*)d_in[1];
    const int*   idx   = (const int*)d_in[2];
    const float* a_exp = (const float*)d_in[3];
    const float* a_num = (const float*)d_in[4];
    const float* coef  = (const float*)d_in[5];
    const float* expo  = (const float*)d_in[6];
    const float* rs    = (const float*)d_in[7];

    float* out = (float*)d_out;
    float* wsf = (float*)d_ws;
    unsigned char* wsb = (unsigned char*)d_ws;

    const int nA = in_sizes[0] / 3;
    const int nE = in_sizes[2] / 2;
    const int* idx_i = idx;
    const int* idx_j = idx + nE;

    const int xyPad = (nA + 15) & ~15;
    const int nibPad = (((nA + 1) >> 1) + 15) & ~15;
    unsigned char* XY = wsb + 512;
    unsigned char* Z4 = XY + xyPad;
    unsigned char* X4 = Z4 + nibPad;
    s4* P8 = (s4*)(X4 + nibPad);

    atom_prep<<<(nA + 255) / 256, 256, 0, stream>>>(R, Z, a_exp, a_num, coef,
                                                    expo, rs, XY, Z4, X4, P8,
                                                    wsf, out, nA);

    // Deterministic per-device path selection (same work every call).
    const int dynBig = xyPad + nibPad;          // 150 KB for nA=100K
    int dev = 0;
    (void)hipGetDevice(&dev);
    int maxShm = 0;
    (void)hipDeviceGetAttribute(&maxShm, hipDeviceAttributeMaxSharedMemoryPerBlock, dev);
    hipFuncAttributes fa{};
    (void)hipFuncGetAttributes(&fa, (const void*)zbl_big);
    const int staticLds = 16 * QCAP * 8 + 256 + 48 + 64 + 64;   // ~12.7 KB
    const bool big = (maxShm >= dynBig + staticLds) ||
                     (fa.maxDynamicSharedSizeBytes >= dynBig);

    if (big) {
        (void)hipFuncSetAttribute((const void*)zbl_big,
                                  hipFuncAttributeMaxDynamicSharedMemorySize, dynBig);
        zbl_big<<<256, 1024, dynBig, stream>>>(XY, Z4, P8, R, idx_i, idx_j,
                                               wsf, out, nE, nA);
    } else {
        zbl_safe<<<512, 1024, nibPad, stream>>>(X4, P8, R, idx_i, idx_j,
                                                wsf, out, nE, nA);
    }
}